// Round 8
// baseline (155.274 us; speedup 1.0000x reference)
//
#include <hip/hip_runtime.h>

// ---------------------------------------------------------------------------
// DeltaModel: B=256, L=2048, H=V=64.
//  (1) hs/k/v/q depend only on token id (V=64) -> 64-entry tables.
//  (2) r = M_N q -> backward scan in token space: y_a = k_a . u,
//        s = y[b_t];  y -= s*G[:,b_t];  r += s*v[b_t],  G[a][b]=k_a.k_b.
//  R6 post-mortem: loop is CHAIN-bound: readlane->fmac->readlane hop costs
//  ~45-60 cyc (VALU->readlane + SGPR forwarding hazards); instr trimming did
//  nothing. R7: batch W=4 steps per hop. Read p0..p3 from y_pre (one hop),
//  correct locally via the 4x4 unit-triangular solve with T[j][i] =
//  G[b_j][b_i] = readlane(prefetched column i, b_j) (off-chain), then apply
//  4 rank-1 updates. 4x fewer sequential hops, same arithmetic.
// ---------------------------------------------------------------------------

#define DPP_ADD_F32(x, ctrl, rm, bm, bc)                                      \
  (x) = (x) + __int_as_float(__builtin_amdgcn_update_dpp(                     \
            0, __float_as_int(x), (ctrl), (rm), (bm), (bc)))

__device__ __forceinline__ float wave_sum64(float x) {
  DPP_ADD_F32(x, 0x111, 0xf, 0xf, true);   // row_shr:1
  DPP_ADD_F32(x, 0x112, 0xf, 0xf, true);   // row_shr:2
  DPP_ADD_F32(x, 0x114, 0xf, 0xf, true);   // row_shr:4
  DPP_ADD_F32(x, 0x118, 0xf, 0xf, true);   // row_shr:8
  DPP_ADD_F32(x, 0x142, 0xa, 0xf, false);  // row_bcast:15
  DPP_ADD_F32(x, 0x143, 0xc, 0xf, false);  // row_bcast:31 -> lane 63 total
  return __int_as_float(__builtin_amdgcn_readlane(__float_as_int(x), 63));
}

__device__ __forceinline__ float readlane_f(float x, int lane) {
  return __int_as_float(__builtin_amdgcn_readlane(__float_as_int(x), lane));
}
#define RLI(v, s) __builtin_amdgcn_readlane((v), (s))

// ---------------------------------------------------------------------------
// Kernel A: per-token tables. 256 threads: 4 waves stage weights into padded
// LDS in parallel; wave 0 does the (wave-wide) compute.
// ---------------------------------------------------------------------------
__global__ __launch_bounds__(256) void build_tables(
    const float* __restrict__ embed, const float* __restrict__ W1,
    const float* __restrict__ b1, const float* __restrict__ W2,
    const float* __restrict__ b2, const float* __restrict__ gamma,
    const float* __restrict__ beta, const float* __restrict__ Wk,
    const float* __restrict__ Wv, const float* __restrict__ Wq,
    float* __restrict__ k_tab, float* __restrict__ v_tab,
    float* __restrict__ q_tab) {
  __shared__ float Wbuf[8448];
  __shared__ float e_s[64];
  __shared__ float f1_s[128];
  __shared__ float hs_s[64];
  const int tok = blockIdx.x;
  const int tid = threadIdx.x;
  const int l = tid & 63;
  const int w = tid >> 6;

  float e = 0.f, hval = 0.f, hs = 0.f;
#pragma unroll 8
  for (int i = 0; i < 32; ++i) {  // W1: wave w stages rows w*32..w*32+31
    const int row = w * 32 + i;
    Wbuf[row * 65 + l] = W1[row * 64 + l];
  }
  if (w == 0) {
    e = embed[tok * 64 + l];
    e_s[l] = e;
  }
  __syncthreads();

  if (w == 0) {
    float a0 = b1[l], a1 = b1[l + 64];
#pragma unroll
    for (int h = 0; h < 64; ++h) {
      a0 = fmaf(e_s[h], Wbuf[l * 65 + h], a0);
      a1 = fmaf(e_s[h], Wbuf[(l + 64) * 65 + h], a1);
    }
    f1_s[l] = fmaxf(a0, 0.f);
    f1_s[l + 64] = fmaxf(a1, 0.f);
  }
  __syncthreads();

#pragma unroll 8
  for (int i = 0; i < 32; ++i) {  // W2 staged as 64 rows of 131 (2x64+pad)
    const int row = w * 32 + i;
    Wbuf[(row >> 1) * 131 + (row & 1) * 64 + l] = W2[row * 64 + l];
  }
  __syncthreads();

  if (w == 0) {
    float acc = b2[l];
#pragma unroll
    for (int j = 0; j < 128; ++j) acc = fmaf(f1_s[j], Wbuf[l * 131 + j], acc);
    hval = e + acc;
    const float mu = wave_sum64(hval) * (1.f / 64.f);
    const float d = hval - mu;
    const float var = wave_sum64(d * d) * (1.f / 64.f);
    hs = d * (1.f / sqrtf(var + 1e-5f)) * gamma[l] + beta[l];
    hs_s[l] = hs;
  }
  __syncthreads();

#pragma unroll 8
  for (int i = 0; i < 16; ++i) {  // Wk+Wv
    const int row = w * 16 + i;
    Wbuf[row * 65 + l] = Wk[row * 64 + l];
    Wbuf[4224 + row * 65 + l] = Wv[row * 64 + l];
  }
  __syncthreads();
  float kk = 0.f, vv = 0.f;
  if (w == 0) {
#pragma unroll
    for (int h = 0; h < 64; ++h) {
      kk = fmaf(hs_s[h], Wbuf[l * 65 + h], kk);
      vv = fmaf(hs_s[h], Wbuf[4224 + l * 65 + h], vv);
    }
  }
  __syncthreads();
#pragma unroll 8
  for (int i = 0; i < 16; ++i) {  // Wq
    const int row = w * 16 + i;
    Wbuf[row * 65 + l] = Wq[row * 64 + l];
  }
  __syncthreads();
  if (w == 0) {
    float qq = 0.f;
#pragma unroll
    for (int h = 0; h < 64; ++h) qq = fmaf(hs_s[h], Wbuf[l * 65 + h], qq);
    float nrm = fmaxf(sqrtf(wave_sum64(kk * kk)), 1e-12f);
    k_tab[tok * 64 + l] = kk / nrm;
    v_tab[tok * 64 + l] = vv;
    q_tab[tok * 64 + l] = qq;
  }
}

// ---------------------------------------------------------------------------
// Kernel B: GV[a][l] = {G[a][l], v[a][l]} float2; KQ[a][l] = q_a.k_l.
// 256 threads: 4 waves stage, wave 0 computes.
// ---------------------------------------------------------------------------
__global__ __launch_bounds__(256) void build_gram(
    const float* __restrict__ k_tab, const float* __restrict__ q_tab,
    const float* __restrict__ v_tab, float2* __restrict__ GV,
    float* __restrict__ KQ) {
  __shared__ float k_s[4160];
  __shared__ float q_s[64];
  const int a = blockIdx.x;
  const int tid = threadIdx.x;
  const int l = tid & 63;
  const int w = tid >> 6;
#pragma unroll 8
  for (int i = 0; i < 16; ++i) {
    const int row = w * 16 + i;
    k_s[row * 65 + l] = k_tab[row * 64 + l];
  }
  if (w == 0) q_s[l] = q_tab[a * 64 + l];
  __syncthreads();
  if (w == 0) {
    float g = 0.f, kq = 0.f;
#pragma unroll
    for (int h = 0; h < 64; ++h) {
      g = fmaf(k_s[a * 65 + h], k_s[l * 65 + h], g);
      kq = fmaf(q_s[h], k_s[l * 65 + h], kq);
    }
    GV[a * 64 + l] = make_float2(g, v_tab[a * 64 + l]);
    KQ[a * 64 + l] = kq;
  }
}

// ---------------------------------------------------------------------------
// Kernel C: per-batch scan + head. One wave per batch; lane a owns y_a.
// 16-step chunks = 4 quads. Per quad: prefetch 4 columns for next chunk,
// extract 6 T entries from THIS quad's (already prefetched) columns, one
// broadcast hop (4 reads of y_pre), local 4x4 triangular correction, 4
// rank-1 updates. Dummy step 0 handled by zeroing bufA[0]: kills its y/r
// update AND its T couplings (column = 0).
// ---------------------------------------------------------------------------

#define CHUNK4(CONS, PREF, SC, SP, TV, PB)                                    \
  _Pragma("unroll") for (int q = 0; q < 4; ++q) {                             \
    _Pragma("unroll") for (int j = 0; j < 4; ++j) {                           \
      SP[4 * q + j] = RLI((TV), (PB) + 4 * q + j);                            \
      PREF[4 * q + j] = GV_s[SP[4 * q + j] * 64 + l];                         \
    }                                                                         \
    const float T10 = readlane_f(CONS[4 * q + 0].x, SC[4 * q + 1]);           \
    const float T20 = readlane_f(CONS[4 * q + 0].x, SC[4 * q + 2]);           \
    const float T30 = readlane_f(CONS[4 * q + 0].x, SC[4 * q + 3]);           \
    const float T21 = readlane_f(CONS[4 * q + 1].x, SC[4 * q + 2]);           \
    const float T31 = readlane_f(CONS[4 * q + 1].x, SC[4 * q + 3]);           \
    const float T32 = readlane_f(CONS[4 * q + 2].x, SC[4 * q + 3]);           \
    const float s0 = readlane_f(y, SC[4 * q + 0]);                            \
    const float p1 = readlane_f(y, SC[4 * q + 1]);                            \
    const float p2 = readlane_f(y, SC[4 * q + 2]);                            \
    const float p3 = readlane_f(y, SC[4 * q + 3]);                            \
    const float s1 = fmaf(-s0, T10, p1);                                      \
    const float s2 = fmaf(-s1, T21, fmaf(-s0, T20, p2));                      \
    const float s3 = fmaf(-s2, T32, fmaf(-s1, T31, fmaf(-s0, T30, p3)));      \
    y = fmaf(-s0, CONS[4 * q + 0].x, y);                                      \
    r = fmaf(s0, CONS[4 * q + 0].y, r);                                       \
    y = fmaf(-s1, CONS[4 * q + 1].x, y);                                      \
    r = fmaf(s1, CONS[4 * q + 1].y, r);                                       \
    y = fmaf(-s2, CONS[4 * q + 2].x, y);                                      \
    r = fmaf(s2, CONS[4 * q + 2].y, r);                                       \
    y = fmaf(-s3, CONS[4 * q + 3].x, y);                                      \
    r = fmaf(s3, CONS[4 * q + 3].y, r);                                       \
  }

__global__ __launch_bounds__(64, 1) void scan_head(
    const int* __restrict__ seq, const float2* __restrict__ GVg,
    const float* __restrict__ KQ, const float* __restrict__ Wrp,
    const float* __restrict__ brp, const float* __restrict__ Wout,
    const float* __restrict__ bout, float* __restrict__ out) {
  __shared__ float2 GV_s[4160];
  __shared__ float tmp[64];
  const int b = blockIdx.x;
  const int l = threadIdx.x;

#pragma unroll
  for (int i = 0; i < 32; ++i)
    ((float4*)GV_s)[l + 64 * i] = ((const float4*)GVg)[l + 64 * i];
  GV_s[4096 + l] = make_float2(0.f, 0.f);

  const int* tokp = seq + b * 2048;
  int tok_cur = tokp[2047 - l];       // body 0: lane m <-> step m, t = 2047-m
  int tok_nxt = tokp[2047 - 64 - l];  // body 1
  __syncthreads();

  const int qt = RLI(tok_cur, 0);  // t=2047 token -> q
  float y = KQ[qt * 64 + l];       // y_a = k_a . q
  float r = 0.f;

  float2 bufA[16], bufB[16];
  int sselA[16], sselB[16];
#pragma unroll
  for (int j = 0; j < 16; ++j) {  // prime chunk 0 (steps 0..15)
    sselA[j] = RLI(tok_cur, j);
    bufA[j] = GV_s[sselA[j] * 64 + l];
  }
  // Step 0 is the dummy (t=2047 is the query position): zero its column in
  // registers. This nullifies its y/r update and its T couplings; ssel[0]
  // stays a real token (<64) so every readlane select is in range.
  bufA[0] = make_float2(0.f, 0.f);

  for (int n = 0; n < 32; ++n) {
    const int tok_fut = (n + 2 <= 31) ? tokp[2047 - 64 * (n + 2) - l] : 0;
    CHUNK4(bufA, bufB, sselA, sselB, tok_cur, 16);
    CHUNK4(bufB, bufA, sselB, sselA, tok_cur, 32);
    CHUNK4(bufA, bufB, sselA, sselB, tok_cur, 48);
    CHUNK4(bufB, bufA, sselB, sselA, tok_nxt, 0);
    tok_cur = tok_nxt;
    tok_nxt = tok_fut;
  }

  // Head: r -> Wrp -> Wout (weights staged padded into GV_s memory)
  float* Wb = (float*)GV_s;
  tmp[l] = r;
#pragma unroll 8
  for (int i = 0; i < 64; ++i) {
    Wb[i * 65 + l] = Wrp[i * 64 + l];
    Wb[4160 + i * 65 + l] = Wout[i * 64 + l];
  }
  __syncthreads();
  float acc = brp[l];
#pragma unroll
  for (int j = 0; j < 64; ++j) acc = fmaf(tmp[j], Wb[l * 65 + j], acc);
  __syncthreads();
  tmp[l] = acc;
  __syncthreads();
  float o = bout[l];
#pragma unroll
  for (int i = 0; i < 64; ++i) o = fmaf(tmp[i], Wb[4160 + l * 65 + i], o);
  out[b * 64 + l] = o;
}

extern "C" void kernel_launch(void* const* d_in, const int* in_sizes, int n_in,
                              void* d_out, int out_size, void* d_ws,
                              size_t ws_size, hipStream_t stream) {
  const int* seq = (const int*)d_in[0];
  const float* embed = (const float*)d_in[1];
  const float* W1 = (const float*)d_in[2];
  const float* b1 = (const float*)d_in[3];
  const float* W2 = (const float*)d_in[4];
  const float* b2 = (const float*)d_in[5];
  const float* gamma = (const float*)d_in[6];
  const float* beta = (const float*)d_in[7];
  const float* Wk = (const float*)d_in[8];
  const float* Wv = (const float*)d_in[9];
  const float* Wq = (const float*)d_in[10];
  const float* Wrp = (const float*)d_in[11];
  const float* brp = (const float*)d_in[12];
  const float* Wout = (const float*)d_in[13];
  const float* bout = (const float*)d_in[14];

  float* wsf = (float*)d_ws;
  float* k_tab = wsf;                   // 4096
  float* v_tab = wsf + 4096;            // 4096
  float* q_tab = wsf + 8192;            // 4096
  float2* GV = (float2*)(wsf + 12288);  // 4096 float2
  float* KQ = wsf + 20480;              // 4096

  build_tables<<<64, 256, 0, stream>>>(embed, W1, b1, W2, b2, gamma, beta, Wk,
                                       Wv, Wq, k_tab, v_tab, q_tab);
  build_gram<<<64, 256, 0, stream>>>(k_tab, q_tab, v_tab, GV, KQ);
  scan_head<<<256, 64, 0, stream>>>(seq, GV, KQ, Wrp, brp, Wout, bout,
                                    (float*)d_out);
}